// Round 3
// baseline (72.828 us; speedup 1.0000x reference)
//
#include <hip/hip_runtime.h>

#define BB 16
#define CC 64
#define DD 16
#define HW 2304   // 48*48
#define HID 16
#define NEG_SLOPE 0.01f

using f4 = __attribute__((ext_vector_type(4))) float;

// Kernel 1: one block per (b,d). 16 waves x 4 channel planes each; pooling
// reads are REGULAR loads so x lands in the 256 MB Infinity Cache (x = 151 MB
// fits entirely) for kernel 2 to hit. Then the tiny 64->16->64 MLP + sigmoid.
__global__ __launch_bounds__(1024) void gate_kernel(
    const float* __restrict__ x,
    const float* __restrict__ w1, const float* __restrict__ b1,
    const float* __restrict__ w2, const float* __restrict__ b2,
    float* __restrict__ gate)
{
    const int bd = blockIdx.x;
    const int b = bd >> 4, d = bd & 15;
    const int wave = threadIdx.x >> 6;
    const int lane = threadIdx.x & 63;

    __shared__ float pooled[CC];
    __shared__ float hbuf[HID];

    #pragma unroll
    for (int i = 0; i < 4; ++i) {
        const int c = wave * 4 + i;
        const f4* p = (const f4*)(x + (((size_t)(b * CC + c) * DD + d) * HW));
        float s = 0.f;
        #pragma unroll
        for (int j = 0; j < 9; ++j) {
            f4 v = p[lane + j * 64];
            s += v.x + v.y + v.z + v.w;
        }
        #pragma unroll
        for (int m = 32; m; m >>= 1) s += __shfl_xor(s, m, 64);
        if (lane == 0) pooled[c] = s * (1.0f / HW);
    }
    __syncthreads();

    if (threadIdx.x < HID) {
        float acc = b1[threadIdx.x];
        #pragma unroll
        for (int c = 0; c < CC; ++c) acc += w1[threadIdx.x * CC + c] * pooled[c];
        hbuf[threadIdx.x] = acc >= 0.f ? acc : NEG_SLOPE * acc;
    }
    __syncthreads();

    if (threadIdx.x < CC) {
        float acc = b2[threadIdx.x];
        #pragma unroll
        for (int o = 0; o < HID; ++o) acc += w2[threadIdx.x * HID + o] * hbuf[o];
        gate[(b * CC + threadIdx.x) * DD + d] = 1.0f / (1.0f + expf(-acc));
    }
}

// Kernel 2: float4 grid-stride multiply. x reads are regular (LLC-hot from
// kernel 1); out stores are NON-TEMPORAL so the 151 MB write stream doesn't
// evict x from the memory-side LLC (this was round-0's 453 MB mistake).
__global__ __launch_bounds__(256) void mul_kernel(
    const float* __restrict__ x,
    const float* __restrict__ gate,
    float* __restrict__ out)
{
    const int N4 = BB * CC * DD * HW / 4;  // 9,437,184
    const int stride = gridDim.x * blockDim.x;
    for (int i = blockIdx.x * blockDim.x + threadIdx.x; i < N4; i += stride) {
        const float gv = gate[i / 576];    // 576 float4 per (b,c,d) plane
        f4 v = ((const f4*)x)[i];
        v.x *= gv; v.y *= gv; v.z *= gv; v.w *= gv;
        __builtin_nontemporal_store(v, (f4*)out + i);
    }
}

extern "C" void kernel_launch(void* const* d_in, const int* in_sizes, int n_in,
                              void* d_out, int out_size, void* d_ws, size_t ws_size,
                              hipStream_t stream) {
    const float* x  = (const float*)d_in[0];
    const float* w1 = (const float*)d_in[1];
    const float* b1 = (const float*)d_in[2];
    const float* w2 = (const float*)d_in[3];
    const float* b2 = (const float*)d_in[4];
    float* out  = (float*)d_out;
    float* gate = (float*)d_ws;   // B*C*D = 16384 floats = 64 KB

    gate_kernel<<<BB * DD, 1024, 0, stream>>>(x, w1, b1, w2, b2, gate);
    mul_kernel<<<2048, 256, 0, stream>>>(x, gate, out);
}

// Round 4
// 64.453 us; speedup vs baseline: 1.1299x; 1.1299x over previous
//
#include <hip/hip_runtime.h>

#define BB 16
#define CC 64
#define DD 16
#define HW 2304     // 48*48
#define HID 16
#define NEG_SLOPE 0.01f
#define CH4 9216    // float4 stride between channels at fixed (b,d) = DD*HW/4

using f4 = __attribute__((ext_vector_type(4))) float;

// Per thread: 4 channels x 9 float4 = 36 float4 of x.
// Storage map (compile-time): 25 in registers, 9 in LDS, 2 re-read from global.
// KIND: 0 = register, 1 = LDS, 2 = re-read.  IDX: register index / LDS slot.
__device__ constexpr int KIND[4][9] = {
    {0,0,0,0,0,0,0, 1,1},
    {0,0,0,0,0,0, 1,1,1},
    {0,0,0,0,0,0, 1,1,1},
    {0,0,0,0,0,0, 1, 2,2},
};
__device__ constexpr int IDX[4][9] = {
    { 0, 1, 2, 3, 4, 5, 6,  0, 1},
    { 7, 8, 9,10,11,12,  2, 3, 4},
    {13,14,15,16,17,18,  5, 6, 7},
    {19,20,21,22,23,24,  8,  0, 0},
};

// One block per (b,d): 16 waves x 4 channels. Pool -> 64->16->64 MLP gate in
// LDS -> multiply, with 34/36 of the slice held on-chip (regs + LDS).
// NT stores keep the write stream from evicting anything useful.
__global__ __launch_bounds__(1024, 4) void fused_se_kernel(
    const float* __restrict__ x,
    const float* __restrict__ w1, const float* __restrict__ b1,
    const float* __restrict__ w2, const float* __restrict__ b2,
    float* __restrict__ out)
{
    const int bd   = blockIdx.x;
    const int b    = bd >> 4;
    const int d    = bd & 15;
    const int tid  = threadIdx.x;
    const int wave = tid >> 6;
    const int lane = tid & 63;

    __shared__ f4 stage[9][1024];          // 147456 B
    __shared__ float pooled[CC];
    __shared__ float hbuf[HID];
    __shared__ float gate_s[CC];

    const size_t base4 = ((size_t)(b * CC) * DD + d) * (HW / 4);
    const f4* xb = (const f4*)x + base4 + lane;

    f4 rv[25];
    float csum[4] = {0.f, 0.f, 0.f, 0.f};

    // ---- Phase 1: read + pool (everything lands in regs or LDS) ----
    #pragma unroll
    for (int i = 0; i < 4; ++i) {
        const f4* p = xb + (size_t)(wave * 4 + i) * CH4;
        #pragma unroll
        for (int s = 0; s < 9; ++s) {
            f4 v = p[s * 64];
            csum[i] += v.x + v.y + v.z + v.w;
            if (KIND[i][s] == 0)      rv[IDX[i][s]] = v;
            else if (KIND[i][s] == 1) stage[IDX[i][s]][tid] = v;
            // KIND 2: summed now, re-read in phase 3
        }
    }
    #pragma unroll
    for (int i = 0; i < 4; ++i) {
        float s = csum[i];
        #pragma unroll
        for (int m = 32; m; m >>= 1) s += __shfl_xor(s, m, 64);
        if (lane == 0) pooled[wave * 4 + i] = s * (1.0f / HW);
    }
    __syncthreads();

    // ---- Phase 2: tiny MLP (64 -> 16 leaky-relu -> 64 sigmoid) ----
    if (tid < HID) {
        float acc = b1[tid];
        #pragma unroll
        for (int c = 0; c < CC; ++c) acc += w1[tid * CC + c] * pooled[c];
        hbuf[tid] = acc >= 0.f ? acc : NEG_SLOPE * acc;
    }
    __syncthreads();
    if (tid < CC) {
        float acc = b2[tid];
        #pragma unroll
        for (int o = 0; o < HID; ++o) acc += w2[tid * HID + o] * hbuf[o];
        gate_s[tid] = 1.0f / (1.0f + expf(-acc));
    }
    __syncthreads();

    // ---- Phase 3: multiply + NT store ----
    // Issue the two re-read loads FIRST so their latency hides under the
    // 34 NT stores below.
    const f4* p3 = xb + (size_t)(wave * 4 + 3) * CH4;
    f4 rr0 = p3[7 * 64];
    f4 rr1 = p3[8 * 64];

    f4* ob = (f4*)out + base4 + lane;
    #pragma unroll
    for (int i = 0; i < 4; ++i) {
        const float gv = gate_s[wave * 4 + i];
        f4* q = ob + (size_t)(wave * 4 + i) * CH4;
        #pragma unroll
        for (int s = 0; s < 9; ++s) {
            if (KIND[i][s] == 2) continue;
            f4 v = (KIND[i][s] == 0) ? rv[IDX[i][s]] : stage[IDX[i][s]][tid];
            v.x *= gv; v.y *= gv; v.z *= gv; v.w *= gv;
            __builtin_nontemporal_store(v, q + s * 64);
        }
    }
    {
        const float gv = gate_s[wave * 4 + 3];
        f4* q = ob + (size_t)(wave * 4 + 3) * CH4;
        f4 v0 = rr0, v1 = rr1;
        v0.x *= gv; v0.y *= gv; v0.z *= gv; v0.w *= gv;
        v1.x *= gv; v1.y *= gv; v1.z *= gv; v1.w *= gv;
        __builtin_nontemporal_store(v0, q + 7 * 64);
        __builtin_nontemporal_store(v1, q + 8 * 64);
    }
}

extern "C" void kernel_launch(void* const* d_in, const int* in_sizes, int n_in,
                              void* d_out, int out_size, void* d_ws, size_t ws_size,
                              hipStream_t stream) {
    const float* x  = (const float*)d_in[0];
    const float* w1 = (const float*)d_in[1];
    const float* b1 = (const float*)d_in[2];
    const float* w2 = (const float*)d_in[3];
    const float* b2 = (const float*)d_in[4];
    float* out = (float*)d_out;

    fused_se_kernel<<<BB * DD, 1024, 0, stream>>>(x, w1, b1, w2, b2, out);
}

// Round 5
// 53.786 us; speedup vs baseline: 1.3540x; 1.1983x over previous
//
#include <hip/hip_runtime.h>

#define BB 16
#define CC 64
#define DD 16
#define HW 2304     // 48*48
#define HID 16
#define NEG_SLOPE 0.01f
#define CH4 9216    // float4 stride between channels at fixed (b,d)

using f4 = __attribute__((ext_vector_type(4))) float;

// Pack 4 fp32 -> 4 bf16 (two dwords). v_cvt_pk_bf16_f32: D.lo=bf16(S0), D.hi=bf16(S1).
__device__ __forceinline__ uint2 pack_bf16x4(f4 v) {
    uint2 r;
    asm("v_cvt_pk_bf16_f32 %0, %1, %2" : "=v"(r.x) : "v"(v.x), "v"(v.y));
    asm("v_cvt_pk_bf16_f32 %0, %1, %2" : "=v"(r.y) : "v"(v.z), "v"(v.w));
    return r;
}

// Unpack bf16x4 and multiply by gate: bf16->f32 is a 16-bit shift / mask.
__device__ __forceinline__ f4 unpack_mul(uint2 p, float g) {
    f4 v;
    v.x = __uint_as_float(p.x << 16) * g;
    v.y = __uint_as_float(p.x & 0xffff0000u) * g;
    v.z = __uint_as_float(p.y << 16) * g;
    v.w = __uint_as_float(p.y & 0xffff0000u) * g;
    return v;
}

// One block per (b,d): 16 waves x 4 channels x 9 float4. The whole slice is
// retained ON-CHIP as bf16: 17 packed slots in registers (34 VGPR) + 19 in
// LDS (155.6 KB). Zero re-read, zero spill. Pool sums use fp32 loads before
// packing; only the multiply operand is bf16 (error ~1e-2 << 5.5e-2 thresh).
__global__ __launch_bounds__(1024) void fused_se_kernel(
    const float* __restrict__ x,
    const float* __restrict__ w1, const float* __restrict__ b1,
    const float* __restrict__ w2, const float* __restrict__ b2,
    float* __restrict__ out)
{
    const int bd   = blockIdx.x;
    const int b    = bd >> 4;
    const int d    = bd & 15;
    const int tid  = threadIdx.x;
    const int wave = tid >> 6;
    const int lane = tid & 63;

    __shared__ uint2 stage[19][1024];      // 155,648 B
    __shared__ float pooled[CC];
    __shared__ float hbuf[HID];
    __shared__ float gate_s[CC];

    const size_t base4 = ((size_t)(b * CC) * DD + d) * (HW / 4);
    const f4* xb = (const f4*)x + base4 + lane;

    // per-channel storage map: ch0 -> 5 reg + 4 LDS, ch1..3 -> 4 reg + 5 LDS
    uint2 rv[17];

    // ---- Phase 1: read + pool + pack on-chip ----
    #pragma unroll
    for (int i = 0; i < 4; ++i) {
        const f4* p = xb + (size_t)(wave * 4 + i) * CH4;
        const int nreg  = (i == 0) ? 5 : 4;
        const int rbase = (i == 0) ? 0 : 5 + (i - 1) * 4;
        const int lbase = (i == 0) ? 0 : 4 + (i - 1) * 5;
        float s = 0.f;
        #pragma unroll
        for (int j = 0; j < 9; ++j) {
            f4 v = p[j * 64];
            s += v.x + v.y + v.z + v.w;           // fp32 pool
            uint2 pk = pack_bf16x4(v);
            if (j < nreg) rv[rbase + j] = pk;
            else          stage[lbase + (j - nreg)][tid] = pk;
        }
        #pragma unroll
        for (int m = 32; m; m >>= 1) s += __shfl_xor(s, m, 64);
        if (lane == 0) pooled[wave * 4 + i] = s * (1.0f / HW);
    }
    __syncthreads();

    // ---- Phase 2: tiny MLP (64 -> 16 leaky-relu -> 64 sigmoid) ----
    if (tid < HID) {
        float acc = b1[tid];
        #pragma unroll
        for (int c = 0; c < CC; ++c) acc += w1[tid * CC + c] * pooled[c];
        hbuf[tid] = acc >= 0.f ? acc : NEG_SLOPE * acc;
    }
    __syncthreads();
    if (tid < CC) {
        float acc = b2[tid];
        #pragma unroll
        for (int o = 0; o < HID; ++o) acc += w2[tid * HID + o] * hbuf[o];
        gate_s[tid] = 1.0f / (1.0f + expf(-acc));
    }
    __syncthreads();

    // ---- Phase 3: unpack, multiply, NT store (write stream only) ----
    f4* ob = (f4*)out + base4 + lane;
    #pragma unroll
    for (int i = 0; i < 4; ++i) {
        const float gv = gate_s[wave * 4 + i];
        f4* q = ob + (size_t)(wave * 4 + i) * CH4;
        const int nreg  = (i == 0) ? 5 : 4;
        const int rbase = (i == 0) ? 0 : 5 + (i - 1) * 4;
        const int lbase = (i == 0) ? 0 : 4 + (i - 1) * 5;
        #pragma unroll
        for (int j = 0; j < 9; ++j) {
            uint2 pk = (j < nreg) ? rv[rbase + j] : stage[lbase + (j - nreg)][tid];
            __builtin_nontemporal_store(unpack_mul(pk, gv), q + j * 64);
        }
    }
}

extern "C" void kernel_launch(void* const* d_in, const int* in_sizes, int n_in,
                              void* d_out, int out_size, void* d_ws, size_t ws_size,
                              hipStream_t stream) {
    const float* x  = (const float*)d_in[0];
    const float* w1 = (const float*)d_in[1];
    const float* b1 = (const float*)d_in[2];
    const float* w2 = (const float*)d_in[3];
    const float* b2 = (const float*)d_in[4];
    float* out = (float*)d_out;

    fused_se_kernel<<<BB * DD, 1024, 0, stream>>>(x, w1, b1, w2, b2, out);
}

// Round 7
// 53.451 us; speedup vs baseline: 1.3625x; 1.0063x over previous
//
#include <hip/hip_runtime.h>

#define BB 16
#define CC 64
#define DD 16
#define HW 2304     // 48*48
#define HID 16
#define NEG_SLOPE 0.01f
#define CH4 9216    // float4 stride between channels at fixed (b,d)

using f4 = __attribute__((ext_vector_type(4))) float;

// Pack 4 fp32 -> 4 bf16 (two dwords). v_cvt_pk_bf16_f32: D.lo=bf16(S0), D.hi=bf16(S1).
__device__ __forceinline__ uint2 pack_bf16x4(f4 v) {
    uint2 r;
    asm("v_cvt_pk_bf16_f32 %0, %1, %2" : "=v"(r.x) : "v"(v.x), "v"(v.y));
    asm("v_cvt_pk_bf16_f32 %0, %1, %2" : "=v"(r.y) : "v"(v.z), "v"(v.w));
    return r;
}

// Unpack bf16x4 and multiply by gate: bf16->f32 is a 16-bit shift / mask.
__device__ __forceinline__ f4 unpack_mul(uint2 p, float g) {
    f4 v;
    v.x = __uint_as_float(p.x << 16) * g;
    v.y = __uint_as_float(p.x & 0xffff0000u) * g;
    v.z = __uint_as_float(p.y << 16) * g;
    v.w = __uint_as_float(p.y & 0xffff0000u) * g;
    return v;
}

// One block per (b,d): 16 waves x 4 channels x 9 float4. Whole slice retained
// on-chip as bf16: 17 packed slots in regs + 19 in LDS (155.6 KB). Zero
// re-read, zero spill. fp32 pooling; bf16 multiply operand (err ~1e-2).
// Stores via __builtin_nontemporal_store (PROVEN: R5 passed; R6's sc1+nt
// inline-asm store scrambled output — reserved CPol combo, do not revisit).
__global__ __launch_bounds__(1024) void fused_se_kernel(
    const float* __restrict__ x,
    const float* __restrict__ w1, const float* __restrict__ b1,
    const float* __restrict__ w2, const float* __restrict__ b2,
    float* __restrict__ out)
{
    const int bd   = blockIdx.x;
    const int b    = bd >> 4;
    const int d    = bd & 15;
    const int tid  = threadIdx.x;
    const int wave = tid >> 6;
    const int lane = tid & 63;

    __shared__ uint2 stage[19][1024];      // 155,648 B
    __shared__ float pooled[CC];
    __shared__ float hbuf[HID];
    __shared__ float gate_s[CC];

    const size_t base4 = ((size_t)(b * CC) * DD + d) * (HW / 4);
    const f4* xb = (const f4*)x + base4 + lane;

    // per-channel storage map: ch0 -> 5 reg + 4 LDS, ch1..3 -> 4 reg + 5 LDS
    uint2 rv[17];

    // ---- Phase 1: read + pool + pack on-chip ----
    #pragma unroll
    for (int i = 0; i < 4; ++i) {
        const f4* p = xb + (size_t)(wave * 4 + i) * CH4;
        const int nreg  = (i == 0) ? 5 : 4;
        const int rbase = (i == 0) ? 0 : 5 + (i - 1) * 4;
        const int lbase = (i == 0) ? 0 : 4 + (i - 1) * 5;
        float s = 0.f;
        #pragma unroll
        for (int j = 0; j < 9; ++j) {
            f4 v = p[j * 64];
            s += (v.x + v.y) + (v.z + v.w);       // pairwise: shorter dep chain
            uint2 pk = pack_bf16x4(v);
            if (j < nreg) rv[rbase + j] = pk;
            else          stage[lbase + (j - nreg)][tid] = pk;
        }
        #pragma unroll
        for (int m = 32; m; m >>= 1) s += __shfl_xor(s, m, 64);
        if (lane == 0) pooled[wave * 4 + i] = s * (1.0f / HW);
    }
    __syncthreads();

    // ---- Phase 2: tiny MLP, wave-parallel layer 1 ----
    // wave w computes hidden[w]: lane c holds w1[w][c]*pooled[c], shuffle-reduce.
    {
        float v = w1[wave * CC + lane] * pooled[lane];
        #pragma unroll
        for (int m = 32; m; m >>= 1) v += __shfl_xor(v, m, 64);
        if (lane == 0) {
            float acc = v + b1[wave];
            hbuf[wave] = acc >= 0.f ? acc : NEG_SLOPE * acc;
        }
    }
    __syncthreads();
    if (tid < CC) {
        float acc = b2[tid];
        #pragma unroll
        for (int o = 0; o < HID; ++o) acc += w2[tid * HID + o] * hbuf[o];
        gate_s[tid] = 1.0f / (1.0f + expf(-acc));
    }
    __syncthreads();

    // ---- Phase 3: unpack, multiply, NT store (write stream only) ----
    f4* ob = (f4*)out + base4 + lane;
    #pragma unroll
    for (int i = 0; i < 4; ++i) {
        const float gv = gate_s[wave * 4 + i];
        f4* q = ob + (size_t)(wave * 4 + i) * CH4;
        const int nreg  = (i == 0) ? 5 : 4;
        const int rbase = (i == 0) ? 0 : 5 + (i - 1) * 4;
        const int lbase = (i == 0) ? 0 : 4 + (i - 1) * 5;
        #pragma unroll
        for (int j = 0; j < 9; ++j) {
            uint2 pk = (j < nreg) ? rv[rbase + j] : stage[lbase + (j - nreg)][tid];
            __builtin_nontemporal_store(unpack_mul(pk, gv), q + j * 64);
        }
    }
}

extern "C" void kernel_launch(void* const* d_in, const int* in_sizes, int n_in,
                              void* d_out, int out_size, void* d_ws, size_t ws_size,
                              hipStream_t stream) {
    const float* x  = (const float*)d_in[0];
    const float* w1 = (const float*)d_in[1];
    const float* b1 = (const float*)d_in[2];
    const float* w2 = (const float*)d_in[3];
    const float* b2 = (const float*)d_in[4];
    float* out = (float*)d_out;

    fused_se_kernel<<<BB * DD, 1024, 0, stream>>>(x, w1, b1, w2, b2, out);
}